// Round 3
// baseline (292.124 us; speedup 1.0000x reference)
//
#include <hip/hip_runtime.h>
#include <cmath>

typedef __attribute__((ext_vector_type(8))) short  short8;   // 8 bf16 = 4 VGPRs
typedef __attribute__((ext_vector_type(4))) float  float4v;  // 4 fp32 acc

constexpr int kB  = 8;
constexpr int kC  = 256;
constexpr int kCQ = 32;
constexpr int kN  = 4096;
constexpr int kE  = 320;
constexpr float kLog2e = 1.44269504088896340736f;
constexpr float kMfix  = 10.0f;   // fixed softmax max (R5-proven: s*log2e within ~±4)

// R7: hardware bf16 convert (RNE, same rounding as the old manual path).
__device__ __forceinline__ uint cvt_pk_bf16(float lo, float hi) {
    uint r;
    asm("v_cvt_pk_bf16_f32 %0, %1, %2" : "=v"(r) : "v"(lo), "v"(hi));
    return r;
}
__device__ __forceinline__ ushort f2bf(float f) {   // fp32 -> bf16 RNE, 1 VALU op
    return (ushort)cvt_pk_bf16(f, 0.0f);
}
__device__ __forceinline__ float bf2f(ushort h) {
    return __uint_as_float((uint)h << 16);
}
// R9: raw v_exp_f32 (2^x). Inputs bounded to [-44, 4] by kMfix -> no range
// fixup needed (exp2f without fast-math emits ~6 ops of denormal handling).
// s_nop 1 covers the TRANS->VALU consumer hazard unconditionally.
__device__ __forceinline__ float exp2_raw(float x) {
    float r;
    asm("v_exp_f32 %0, %1\n\ts_nop 1" : "=v"(r) : "v"(x));
    return r;
}

// ---------------------------------------------------------------------------
// Prep: pack wv|wq*log2e|wk into Wb[320][256] bf16, biases into bb[320] f32.
// ---------------------------------------------------------------------------
__global__ __launch_bounds__(256) void prep_kernel(
    const float* __restrict__ wq, const float* __restrict__ bq,
    const float* __restrict__ wk, const float* __restrict__ bk,
    const float* __restrict__ wv, const float* __restrict__ bv,
    ushort* __restrict__ Wb, float* __restrict__ bb)
{
    const int e = blockIdx.x;
    const int c = threadIdx.x;
    const float* src; float bsrc; float scale = 1.0f;
    if (e < 256)      { src = wv + (size_t)e * kC;        bsrc = bv[e]; }
    else if (e < 288) { src = wq + (size_t)(e-256) * kC;  bsrc = bq[e-256]; scale = kLog2e; }
    else              { src = wk + (size_t)(e-288) * kC;  bsrc = bk[e-288]; }
    Wb[(size_t)e * kC + c] = f2bf(src[c] * scale);
    if (c == 0) bb[e] = bsrc * scale;
}

// ---------------------------------------------------------------------------
// MFMA projection GEMM: D[e][n] = sum_c Wb[e][c]*x[b][c][n], e in [0,320).
// grid (128, 8), block 256 (4 waves), 4 blocks/CU.
// ---------------------------------------------------------------------------
__global__ __launch_bounds__(256, 4) void proj_kernel(
    const float* __restrict__ x,
    const ushort* __restrict__ Wb, const float* __restrict__ bb,
    ushort* __restrict__ Qn, ushort* __restrict__ Kn, ushort* __restrict__ Vc)
{
    // union: phase1 = xF[32][264] (8448 us); phase2 = vreg[256][40] (10240 us)
    //        + Tq[32][72] (2304 us) at offset 10240.
    __shared__ __align__(16) ushort u_s[12544];   // 25.1 KB

    const int t    = threadIdx.x;
    const int b    = blockIdx.y;
    const int n0   = blockIdx.x * 32;
    const int lane = t & 63;
    const int w    = t >> 6;
    const int col  = lane & 15;
    const int quad = lane >> 4;

    // ---- stage x[b][0:256][n0:n0+32] -> xF[n][c] (bf16, transposed) ----
    {
        const int n4 = t & 7;
        const int cb = t >> 3;
#pragma unroll
        for (int r = 0; r < 2; ++r) {
            const int c0 = r * 128 + cb * 4;
            float4 L[4];
#pragma unroll
            for (int i = 0; i < 4; ++i)
                L[i] = *(const float4*)(x + ((size_t)b * kC + c0 + i) * kN + n0 + n4 * 4);
#pragma unroll
            for (int jj = 0; jj < 4; ++jj) {
                uint2 pk;
                pk.x = cvt_pk_bf16(((const float*)&L[0])[jj], ((const float*)&L[1])[jj]);
                pk.y = cvt_pk_bf16(((const float*)&L[2])[jj], ((const float*)&L[3])[jj]);
                *(uint2*)&u_s[(n4 * 4 + jj) * 264 + c0] = pk;
            }
        }
    }
    __syncthreads();

    float4v acc[5][2];
#pragma unroll
    for (int mt = 0; mt < 5; ++mt)
#pragma unroll
        for (int nt = 0; nt < 2; ++nt) acc[mt][nt] = float4v{0.f, 0.f, 0.f, 0.f};

    const ushort* ap[5];
#pragma unroll
    for (int mt = 0; mt < 5; ++mt)
        ap[mt] = Wb + ((size_t)(w * 80 + mt * 16 + col)) * kC + quad * 8;

#pragma unroll
    for (int kc = 0; kc < 8; ++kc) {
        short8 bf[2];
#pragma unroll
        for (int nt = 0; nt < 2; ++nt)
            bf[nt] = *(const short8*)&u_s[(nt * 16 + col) * 264 + kc * 32 + quad * 8];
#pragma unroll
        for (int mt = 0; mt < 5; ++mt) {
            const short8 af = *(const short8*)(ap[mt] + kc * 32);
#pragma unroll
            for (int nt = 0; nt < 2; ++nt)
                acc[mt][nt] = __builtin_amdgcn_mfma_f32_16x16x32_bf16(af, bf[nt], acc[mt][nt], 0, 0, 0);
        }
    }
    __syncthreads();   // xF dead; u_s becomes vreg/Tq

    // ---- epilogue: +bias -> LDS repack ----
#pragma unroll
    for (int mt = 0; mt < 5; ++mt) {
        const int e_t = w * 80 + mt * 16;
        const float4 b4 = *(const float4*)(bb + e_t + quad * 4);
#pragma unroll
        for (int nt = 0; nt < 2; ++nt) {
#pragma unroll
            for (int rr = 0; rr < 4; ++rr) {
                const int e = e_t + quad * 4 + rr;
                const ushort v = f2bf(acc[mt][nt][rr] + ((const float*)&b4)[rr]);
                if (e < 256) u_s[e * 40 + nt * 16 + col] = v;                      // vreg[e][n]
                else         u_s[10240 + (nt * 16 + col) * 72 + (e - 256)] = v;    // Tq[n][e']
            }
        }
    }
    __syncthreads();

    // ---- V stores: 1024 tasks of 16B (rows e, 8n chunks) ----
#pragma unroll
    for (int k = 0; k < 4; ++k) {
        const int task = k * 256 + t;
        const int row = task >> 2, chunk = task & 3;
        short8 v = *(const short8*)&u_s[row * 40 + chunk * 8];
        *(short8*)(Vc + ((size_t)b * kC + row) * kN + n0 + chunk * 8) = v;
    }
    // ---- Q/K stores: 256 tasks of 16B ----
    {
        const int n_l = t >> 3, chunk = t & 7;
        short8 v = *(const short8*)&u_s[10240 + n_l * 72 + chunk * 8];
        ushort* dst = (chunk < 4)
            ? (Qn + ((size_t)b * kN + n0 + n_l) * kCQ + chunk * 8)
            : (Kn + ((size_t)b * kN + n0 + n_l) * kCQ + (chunk - 4) * 8);
        *(short8*)dst = v;
    }
}

// ---------------------------------------------------------------------------
// MFMA flash attention, fixed-max softmax.
// R9 restructure: 4-wave blocks (256 thr), per-wave O-tile 64q x 32ch
// (acc = 32 AGPR, was 64), no key-half split, no cross-group merge.
// grid flat 1024 = 8 b x 2 chb x 64 qb -> 4 blocks/CU, 16 waves/CU,
// each SIMD carries 4 waves from 4 INDEPENDENT blocks (barriers decorrelate).
// Register budget: 32 AGPR + ~85 VGPR < 128 -> compiler can keep all
// loads in flight (R8 diagnosis: 64-VGPR straitjacket serialized memory).
// Per block: 64 queries x 128 channels x all 4096 keys, 64 tiles of 64 keys.
// Wave wq computes S for queries wq*16..+16 (4 S-MFMA), shares P via LDS
// (one barrier per tile), PV: 2 ch-mt x 4 q-nt x 2 key-halves = 16 MFMA.
// R8: b = bid&7 keeps one batch per XCD (K/V L2-resident).
// R7 pipeline kept: produce P(t+1) overlapped with PV(t), double-buffered.
// ---------------------------------------------------------------------------
__global__ __launch_bounds__(256, 4) void attn_kernel(
    const ushort* __restrict__ Qn, const ushort* __restrict__ Kn,
    const ushort* __restrict__ Vc,
    const float* __restrict__ x, const float* __restrict__ gptr,
    float* __restrict__ out)
{
    __shared__ __align__(16) ushort p_s[2][4608];   // [buf][64*72] 18.4 KB
    __shared__ float li_s[64];
    __shared__ float linv_s[64];

    const int t    = threadIdx.x;
    const int bid  = blockIdx.x;
    const int b    = bid & 7;        // XCD id under round-robin dispatch
    const int rest = bid >> 3;       // 0..127
    const int chb  = rest & 1;       // channel half (128 ch)
    const int qb   = rest >> 1;      // 0..63
    const int wq   = t >> 6;         // wave = query sub-block AND ch sub-block
    const int lane = t & 63;
    const int col  = lane & 15;
    const int quad = lane >> 4;

    const short8 qfrag = *(const short8*)(
        Qn + ((size_t)b * kN + qb * 64 + wq * 16 + col) * kCQ + quad * 8);

    const ushort* kp = Kn + ((size_t)b * kN + col) * kCQ + quad * 8;
    const ushort* vp[2];
#pragma unroll
    for (int mt = 0; mt < 2; ++mt)
        vp[mt] = Vc + ((size_t)b * kC + chb * 128 + wq * 32 + mt * 16 + col) * kN + quad * 8;

    float4v acc[2][4];
#pragma unroll
    for (int mt = 0; mt < 2; ++mt)
#pragma unroll
        for (int nt = 0; nt < 4; ++nt) acc[mt][nt] = float4v{0.f, 0.f, 0.f, 0.f};
    float lsum = 0.f;
    const float4v mInit = {-kMfix, -kMfix, -kMfix, -kMfix};

    float4v s[4];
    uint    pk[8];

    // load current K tile, issue S^T = K·Q^T - M (C-operand carries -M)
    auto loadK_S = [&]() {
        short8 kf[4];
#pragma unroll
        for (int mt = 0; mt < 4; ++mt) kf[mt] = *(const short8*)(kp + mt * 512);
#pragma unroll
        for (int mt = 0; mt < 4; ++mt)
            s[mt] = __builtin_amdgcn_mfma_f32_16x16x32_bf16(kf[mt], qfrag, mInit, 0, 0, 0);
        kp += 2048;   // 64 keys * 32 us
    };
    // P = exp2(s); accumulate l; pack to bf16 pairs (8 regs carried)
    auto finishP = [&]() {
#pragma unroll
        for (int mt = 0; mt < 4; ++mt) {
            const float p0 = exp2_raw(s[mt][0]);
            const float p1 = exp2_raw(s[mt][1]);
            const float p2 = exp2_raw(s[mt][2]);
            const float p3 = exp2_raw(s[mt][3]);
            lsum += (p0 + p1) + (p2 + p3);
            pk[2 * mt]     = cvt_pk_bf16(p0, p1);
            pk[2 * mt + 1] = cvt_pk_bf16(p2, p3);
        }
    };
    auto writeP = [&](ushort* dst) {
        const int row_base = (wq * 16 + col) * 72;
#pragma unroll
        for (int mt = 0; mt < 4; ++mt) {
            uint2 wv2; wv2.x = pk[2 * mt]; wv2.y = pk[2 * mt + 1];
            *(uint2*)&dst[row_base + mt * 16 + quad * 4] = wv2;
        }
    };
    // consume one 32-key half h of P tile in LDS buffer `buf`
    auto pvHalf = [&](const ushort* buf, int h) {
        short8 vf[2], pf[4];
#pragma unroll
        for (int mt = 0; mt < 2; ++mt) vf[mt] = *(const short8*)(vp[mt] + h * 32);
#pragma unroll
        for (int nt = 0; nt < 4; ++nt)
            pf[nt] = *(const short8*)&buf[(nt * 16 + col) * 72 + h * 32 + quad * 8];
#pragma unroll
        for (int mt = 0; mt < 2; ++mt)
#pragma unroll
            for (int nt = 0; nt < 4; ++nt)
                acc[mt][nt] = __builtin_amdgcn_mfma_f32_16x16x32_bf16(vf[mt], pf[nt], acc[mt][nt], 0, 0, 0);
    };

    // ---- prologue: produce P(0) into buf0 ----
    loadK_S();
    finishP();
    writeP(&p_s[0][0]);
    __syncthreads();

    // ---- pipelined main loop: consume P(t), produce P(t+1) ----
    for (int tile = 0; tile < 63; ++tile) {
        const ushort* cur = &p_s[tile & 1][0];
        ushort*       nxt = &p_s[(tile & 1) ^ 1][0];

        loadK_S();          // K(t+1) + S(t+1) issue
        pvHalf(cur, 0);
        finishP();          // exp/pack(t+1) under PV
        pvHalf(cur, 1);
#pragma unroll
        for (int mt = 0; mt < 2; ++mt) vp[mt] += 64;

        writeP(nxt);        // P(t+1) -> other buffer
        __syncthreads();
    }

    // ---- tail: consume P(63) (buf1) ----
    pvHalf(&p_s[1][0], 0);
    pvHalf(&p_s[1][0], 1);

    // ---- l: per-wave full row sums (no cross-group merge needed) ----
    lsum += __shfl_xor(lsum, 16);
    lsum += __shfl_xor(lsum, 32);
    if (quad == 0) li_s[wq * 16 + col] = lsum;
    __syncthreads();
    if (t < 64) linv_s[t] = 1.0f / li_s[t];
    __syncthreads();

    // ---- epilogue: direct f32 stores, acc stays f32 throughout ----
    const float gm = gptr[0];
#pragma unroll
    for (int mt = 0; mt < 2; ++mt) {
#pragma unroll
        for (int nt = 0; nt < 4; ++nt) {
            const float li = linv_s[nt * 16 + col];
#pragma unroll
            for (int r = 0; r < 4; ++r) {
                const int ch = chb * 128 + wq * 32 + mt * 16 + quad * 4 + r;
                const size_t idx = ((size_t)b * kC + ch) * kN + qb * 64 + nt * 16 + col;
                out[idx] = gm * acc[mt][nt][r] * li + x[idx];
            }
        }
    }
}

extern "C" void kernel_launch(void* const* d_in, const int* in_sizes, int n_in,
                              void* d_out, int out_size, void* d_ws, size_t ws_size,
                              hipStream_t stream)
{
    const float* x  = (const float*)d_in[0];
    const float* wq = (const float*)d_in[1];
    const float* bq = (const float*)d_in[2];
    const float* wk = (const float*)d_in[3];
    const float* bk = (const float*)d_in[4];
    const float* wv = (const float*)d_in[5];
    const float* bv = (const float*)d_in[6];
    const float* gm = (const float*)d_in[7];
    float* out = (float*)d_out;

    ushort* Qn = (ushort*)d_ws;                         // [8][4096][32] bf16, 2 MB
    ushort* Kn = Qn + (size_t)kB * kN * kCQ;            // [8][4096][32] bf16, 2 MB
    ushort* Vc = Kn + (size_t)kB * kN * kCQ;            // [8][256][4096] bf16, 16 MB
    ushort* Wb = Vc + (size_t)kB * kC * kN;             // [320][256] bf16, 160 KB
    float*  bb = (float*)(Wb + (size_t)kE * kC);        // [320] f32

    prep_kernel<<<dim3(kE), 256, 0, stream>>>(wq, bq, wk, bk, wv, bv, Wb, bb);
    proj_kernel<<<dim3(128, 8), 256, 0, stream>>>(x, Wb, bb, Qn, Kn, Vc);
    // R9: flat grid 1024 = 8 b x 2 chb x 64 qb, 256-thread blocks
    attn_kernel<<<dim3(1024), 256, 0, stream>>>(Qn, Kn, Vc, x, gm, out);
}

// Round 4
// 264.455 us; speedup vs baseline: 1.1046x; 1.1046x over previous
//
#include <hip/hip_runtime.h>
#include <cmath>

typedef __attribute__((ext_vector_type(8))) short  short8;   // 8 bf16 = 4 VGPRs
typedef __attribute__((ext_vector_type(4))) float  float4v;  // 4 fp32 acc

constexpr int kB  = 8;
constexpr int kC  = 256;
constexpr int kCQ = 32;
constexpr int kN  = 4096;
constexpr int kE  = 320;
constexpr float kLog2e = 1.44269504088896340736f;
constexpr float kMfix  = 10.0f;   // fixed softmax max (R5-proven: s*log2e within ~±4)

// R7: hardware bf16 convert (RNE, same rounding as the old manual path).
__device__ __forceinline__ uint cvt_pk_bf16(float lo, float hi) {
    uint r;
    asm("v_cvt_pk_bf16_f32 %0, %1, %2" : "=v"(r) : "v"(lo), "v"(hi));
    return r;
}
__device__ __forceinline__ ushort f2bf(float f) {   // fp32 -> bf16 RNE, 1 VALU op
    return (ushort)cvt_pk_bf16(f, 0.0f);
}
__device__ __forceinline__ float bf2f(ushort h) {
    return __uint_as_float((uint)h << 16);
}
// R9: raw v_exp_f32 (2^x). Inputs bounded to ~[-14,-6] by kMfix -> normal range,
// no fixup needed. s_nop 1 covers the TRANS->VALU consumer hazard.
__device__ __forceinline__ float exp2_raw(float x) {
    float r;
    asm("v_exp_f32 %0, %1\n\ts_nop 1" : "=v"(r) : "v"(x));
    return r;
}

// ---------------------------------------------------------------------------
// Prep: pack wv|wq*log2e|wk into Wb[320][256] bf16, biases into bb[320] f32.
// ---------------------------------------------------------------------------
__global__ __launch_bounds__(256) void prep_kernel(
    const float* __restrict__ wq, const float* __restrict__ bq,
    const float* __restrict__ wk, const float* __restrict__ bk,
    const float* __restrict__ wv, const float* __restrict__ bv,
    ushort* __restrict__ Wb, float* __restrict__ bb)
{
    const int e = blockIdx.x;
    const int c = threadIdx.x;
    const float* src; float bsrc; float scale = 1.0f;
    if (e < 256)      { src = wv + (size_t)e * kC;        bsrc = bv[e]; }
    else if (e < 288) { src = wq + (size_t)(e-256) * kC;  bsrc = bq[e-256]; scale = kLog2e; }
    else              { src = wk + (size_t)(e-288) * kC;  bsrc = bk[e-288]; }
    Wb[(size_t)e * kC + c] = f2bf(src[c] * scale);
    if (c == 0) bb[e] = bsrc * scale;
}

// ---------------------------------------------------------------------------
// MFMA projection GEMM: D[e][n] = sum_c Wb[e][c]*x[b][c][n], e in [0,320).
// grid (128, 8), block 256 (4 waves), 4 blocks/CU.  (unchanged this round)
// ---------------------------------------------------------------------------
__global__ __launch_bounds__(256, 4) void proj_kernel(
    const float* __restrict__ x,
    const ushort* __restrict__ Wb, const float* __restrict__ bb,
    ushort* __restrict__ Qn, ushort* __restrict__ Kn, ushort* __restrict__ Vc)
{
    __shared__ __align__(16) ushort u_s[12544];   // 25.1 KB

    const int t    = threadIdx.x;
    const int b    = blockIdx.y;
    const int n0   = blockIdx.x * 32;
    const int lane = t & 63;
    const int w    = t >> 6;
    const int col  = lane & 15;
    const int quad = lane >> 4;

    // ---- stage x[b][0:256][n0:n0+32] -> xF[n][c] (bf16, transposed) ----
    {
        const int n4 = t & 7;
        const int cb = t >> 3;
#pragma unroll
        for (int r = 0; r < 2; ++r) {
            const int c0 = r * 128 + cb * 4;
            float4 L[4];
#pragma unroll
            for (int i = 0; i < 4; ++i)
                L[i] = *(const float4*)(x + ((size_t)b * kC + c0 + i) * kN + n0 + n4 * 4);
#pragma unroll
            for (int jj = 0; jj < 4; ++jj) {
                uint2 pk;
                pk.x = cvt_pk_bf16(((const float*)&L[0])[jj], ((const float*)&L[1])[jj]);
                pk.y = cvt_pk_bf16(((const float*)&L[2])[jj], ((const float*)&L[3])[jj]);
                *(uint2*)&u_s[(n4 * 4 + jj) * 264 + c0] = pk;
            }
        }
    }
    __syncthreads();

    float4v acc[5][2];
#pragma unroll
    for (int mt = 0; mt < 5; ++mt)
#pragma unroll
        for (int nt = 0; nt < 2; ++nt) acc[mt][nt] = float4v{0.f, 0.f, 0.f, 0.f};

    const ushort* ap[5];
#pragma unroll
    for (int mt = 0; mt < 5; ++mt)
        ap[mt] = Wb + ((size_t)(w * 80 + mt * 16 + col)) * kC + quad * 8;

#pragma unroll
    for (int kc = 0; kc < 8; ++kc) {
        short8 bf[2];
#pragma unroll
        for (int nt = 0; nt < 2; ++nt)
            bf[nt] = *(const short8*)&u_s[(nt * 16 + col) * 264 + kc * 32 + quad * 8];
#pragma unroll
        for (int mt = 0; mt < 5; ++mt) {
            const short8 af = *(const short8*)(ap[mt] + kc * 32);
#pragma unroll
            for (int nt = 0; nt < 2; ++nt)
                acc[mt][nt] = __builtin_amdgcn_mfma_f32_16x16x32_bf16(af, bf[nt], acc[mt][nt], 0, 0, 0);
        }
    }
    __syncthreads();   // xF dead; u_s becomes vreg/Tq

    // ---- epilogue: +bias -> LDS repack ----
#pragma unroll
    for (int mt = 0; mt < 5; ++mt) {
        const int e_t = w * 80 + mt * 16;
        const float4 b4 = *(const float4*)(bb + e_t + quad * 4);
#pragma unroll
        for (int nt = 0; nt < 2; ++nt) {
#pragma unroll
            for (int rr = 0; rr < 4; ++rr) {
                const int e = e_t + quad * 4 + rr;
                const ushort v = f2bf(acc[mt][nt][rr] + ((const float*)&b4)[rr]);
                if (e < 256) u_s[e * 40 + nt * 16 + col] = v;                      // vreg[e][n]
                else         u_s[10240 + (nt * 16 + col) * 72 + (e - 256)] = v;    // Tq[n][e']
            }
        }
    }
    __syncthreads();

    // ---- V stores: 1024 tasks of 16B (rows e, 8n chunks) ----
#pragma unroll
    for (int k = 0; k < 4; ++k) {
        const int task = k * 256 + t;
        const int row = task >> 2, chunk = task & 3;
        short8 v = *(const short8*)&u_s[row * 40 + chunk * 8];
        *(short8*)(Vc + ((size_t)b * kC + row) * kN + n0 + chunk * 8) = v;
    }
    // ---- Q/K stores: 256 tasks of 16B ----
    {
        const int n_l = t >> 3, chunk = t & 7;
        short8 v = *(const short8*)&u_s[10240 + n_l * 72 + chunk * 8];
        ushort* dst = (chunk < 4)
            ? (Qn + ((size_t)b * kN + n0 + n_l) * kCQ + chunk * 8)
            : (Kn + ((size_t)b * kN + n0 + n_l) * kCQ + (chunk - 4) * 8);
        *(short8*)dst = v;
    }
}

// ---------------------------------------------------------------------------
// R10: barrier-free MFMA flash attention, fixed-max softmax.
// Each WAVE owns a full 64q x 64ch output tile and is fully independent:
// it computes its own S (4-way duplicated across the block's 4 ch-waves,
// +33% MFMA -- the price of killing the LDS P-path), then redistributes
// P from the S-MFMA D-layout to the PV B-operand layout IN REGISTERS:
//   pair (w[2h][rp], w[2h+1][rp]) --permlane32_swap--> --permlane16_swap-->
//   exactly B-frag words (W_rp, W_rp+2) of key-chunk h.    8 swaps/q-frag.
// NO __syncthreads in the whole kernel; no LDS at all. K(t+1) + V
// prefetched in registers -- compiler pipelines freely across tiles
// (R7-R9 post-mortems: the per-tile barrier + vmcnt drain was the wall).
// Block 256 thr = 4 waves = 4 ch-tiles of same 64 queries (shared K in L1).
// grid flat 512 = 64 qT x 8 b; b = bid&7 keeps one batch per XCD (R8).
// __launch_bounds__(256,2): 2 waves/SIMD at <=256 regs (peak ~220, no spill).
// ---------------------------------------------------------------------------
__global__ __launch_bounds__(256, 2) void attn_kernel(
    const ushort* __restrict__ Qn, const ushort* __restrict__ Kn,
    const ushort* __restrict__ Vc,
    const float* __restrict__ x, const float* __restrict__ gptr,
    float* __restrict__ out)
{
    const int t    = threadIdx.x;
    const int bid  = blockIdx.x;
    const int b    = bid & 7;        // XCD id under round-robin dispatch
    const int qT   = bid >> 3;       // 0..63
    const int w    = t >> 6;         // ch tile (64 ch per wave)
    const int lane = t & 63;
    const int col  = lane & 15;
    const int quad = lane >> 4;

    // Q fragments: 64 queries (B-operand: col=q, k=dim)
    short8 qfrag[4];
#pragma unroll
    for (int nt = 0; nt < 4; ++nt)
        qfrag[nt] = *(const short8*)(
            Qn + ((size_t)b * kN + qT * 64 + nt * 16 + col) * kCQ + quad * 8);

    const ushort* kp = Kn + ((size_t)b * kN + col) * kCQ + quad * 8;
    const ushort* vp[4];
#pragma unroll
    for (int mt = 0; mt < 4; ++mt)
        vp[mt] = Vc + ((size_t)b * kC + w * 64 + mt * 16 + col) * kN + quad * 8;

    float4v acc[4][4];   // [ch-mt][q-nt], 64 AGPR
#pragma unroll
    for (int mt = 0; mt < 4; ++mt)
#pragma unroll
        for (int nt = 0; nt < 4; ++nt) acc[mt][nt] = float4v{0.f, 0.f, 0.f, 0.f};
    float lsum[4] = {0.f, 0.f, 0.f, 0.f};
    const float4v mInit = {-kMfix, -kMfix, -kMfix, -kMfix};

    // prefetch K tile 0
    short8 kf[4];
#pragma unroll
    for (int mt = 0; mt < 4; ++mt) kf[mt] = *(const short8*)(kp + mt * 512);

    for (int tile = 0; tile < 64; ++tile) {
        // ---- prefetch next K (hidden under this tile's S+exp+PV) ----
        short8 kn_[4];
        {
            const ushort* kpn = kp + (tile < 63 ? 2048 : 0);
#pragma unroll
            for (int mt = 0; mt < 4; ++mt) kn_[mt] = *(const short8*)(kpn + mt * 512);
        }
        // ---- prefetch V h0 (hidden under S+exp) ----
        short8 vf0[4];
#pragma unroll
        for (int mt = 0; mt < 4; ++mt) vf0[mt] = *(const short8*)(vp[mt]);

        // ---- S + softmax + in-register P redistribution, nt-pairs to cap
        //      live s[] at 32 regs ----
        short8 pfB[4][2];    // [q-nt][key-half]  B-operand fragments
#pragma unroll
        for (int np = 0; np < 2; ++np) {
            float4v s[2][4];
#pragma unroll
            for (int n2 = 0; n2 < 2; ++n2)
#pragma unroll
                for (int mt = 0; mt < 4; ++mt)
                    s[n2][mt] = __builtin_amdgcn_mfma_f32_16x16x32_bf16(
                        kf[mt], qfrag[np * 2 + n2], mInit, 0, 0, 0);
#pragma unroll
            for (int n2 = 0; n2 < 2; ++n2) {
                const int nt = np * 2 + n2;
                uint wv_[4][2];
#pragma unroll
                for (int mt = 0; mt < 4; ++mt) {
                    const float p0 = exp2_raw(s[n2][mt][0]);
                    const float p1 = exp2_raw(s[n2][mt][1]);
                    const float p2 = exp2_raw(s[n2][mt][2]);
                    const float p3 = exp2_raw(s[n2][mt][3]);
                    lsum[nt] += (p0 + p1) + (p2 + p3);
                    wv_[mt][0] = cvt_pk_bf16(p0, p1);
                    wv_[mt][1] = cvt_pk_bf16(p2, p3);
                }
                // quad redistribution: (w[2h][rp], w[2h+1][rp]) -> (W_rp, W_rp+2)
#pragma unroll
                for (int h = 0; h < 2; ++h) {
                    uint W0, W1, W2, W3;
                    {
                        uint a = wv_[h * 2][0], c = wv_[h * 2 + 1][0];
                        asm("v_permlane32_swap_b32 %0, %1" : "+v"(a), "+v"(c));
                        asm("v_permlane16_swap_b32 %0, %1" : "+v"(a), "+v"(c));
                        W0 = a; W2 = c;
                    }
                    {
                        uint a = wv_[h * 2][1], c = wv_[h * 2 + 1][1];
                        asm("v_permlane32_swap_b32 %0, %1" : "+v"(a), "+v"(c));
                        asm("v_permlane16_swap_b32 %0, %1" : "+v"(a), "+v"(c));
                        W1 = a; W3 = c;
                    }
                    uint4 u; u.x = W0; u.y = W1; u.z = W2; u.w = W3;
                    pfB[nt][h] = __builtin_bit_cast(short8, u);
                }
            }
        }

        // ---- prefetch V h1 (hidden under PV h0) ----
        short8 vf1[4];
#pragma unroll
        for (int mt = 0; mt < 4; ++mt) vf1[mt] = *(const short8*)(vp[mt] + 32);

        // ---- PV h0 ----
#pragma unroll
        for (int mt = 0; mt < 4; ++mt)
#pragma unroll
            for (int nt = 0; nt < 4; ++nt)
                acc[mt][nt] = __builtin_amdgcn_mfma_f32_16x16x32_bf16(
                    vf0[mt], pfB[nt][0], acc[mt][nt], 0, 0, 0);
        // ---- PV h1 ----
#pragma unroll
        for (int mt = 0; mt < 4; ++mt)
#pragma unroll
            for (int nt = 0; nt < 4; ++nt)
                acc[mt][nt] = __builtin_amdgcn_mfma_f32_16x16x32_bf16(
                    vf1[mt], pfB[nt][1], acc[mt][nt], 0, 0, 0);

        // ---- advance ----
#pragma unroll
        for (int mt = 0; mt < 4; ++mt) { kf[mt] = kn_[mt]; vp[mt] += 64; }
        kp += 2048;
    }

    // ---- l: reduce over quads (keys were spread quad*4+r) ----
#pragma unroll
    for (int nt = 0; nt < 4; ++nt) {
        lsum[nt] += __shfl_xor(lsum[nt], 16);
        lsum[nt] += __shfl_xor(lsum[nt], 32);
        lsum[nt] = 1.0f / lsum[nt];
    }

    // ---- epilogue: out = gamma * O/l + x (per-lane scalar, lane-coalesced) ----
    const float gm = gptr[0];
#pragma unroll
    for (int mt = 0; mt < 4; ++mt)
#pragma unroll
        for (int nt = 0; nt < 4; ++nt) {
            const float li = lsum[nt];
#pragma unroll
            for (int r = 0; r < 4; ++r) {
                const int ch = w * 64 + mt * 16 + quad * 4 + r;
                const size_t idx = ((size_t)b * kC + ch) * kN + qT * 64 + nt * 16 + col;
                out[idx] = gm * acc[mt][nt][r] * li + x[idx];
            }
        }
}

extern "C" void kernel_launch(void* const* d_in, const int* in_sizes, int n_in,
                              void* d_out, int out_size, void* d_ws, size_t ws_size,
                              hipStream_t stream)
{
    const float* x  = (const float*)d_in[0];
    const float* wq = (const float*)d_in[1];
    const float* bq = (const float*)d_in[2];
    const float* wk = (const float*)d_in[3];
    const float* bk = (const float*)d_in[4];
    const float* wv = (const float*)d_in[5];
    const float* bv = (const float*)d_in[6];
    const float* gm = (const float*)d_in[7];
    float* out = (float*)d_out;

    ushort* Qn = (ushort*)d_ws;                         // [8][4096][32] bf16, 2 MB
    ushort* Kn = Qn + (size_t)kB * kN * kCQ;            // [8][4096][32] bf16, 2 MB
    ushort* Vc = Kn + (size_t)kB * kN * kCQ;            // [8][256][4096] bf16, 16 MB
    ushort* Wb = Vc + (size_t)kB * kC * kN;             // [320][256] bf16, 160 KB
    float*  bb = (float*)(Wb + (size_t)kE * kC);        // [320] f32

    prep_kernel<<<dim3(kE), 256, 0, stream>>>(wq, bq, wk, bk, wv, bv, Wb, bb);
    proj_kernel<<<dim3(128, 8), 256, 0, stream>>>(x, Wb, bb, Qn, Kn, Vc);
    // R10: flat grid 512 = 64 qT x 8 b, 256-thread barrier-free blocks
    attn_kernel<<<dim3(512), 256, 0, stream>>>(Qn, Kn, Vc, x, gm, out);
}